// Round 1
// baseline (1619.616 us; speedup 1.0000x reference)
//
#include <hip/hip_runtime.h>

#define N_NODES 50000
#define N_EDGES 800000
#define D_IN    512
#define D_OUT   128
#define N_SUP   2

// ---------------------------------------------------------------------------
// GEMM: pre[s] = x @ kernels[s]   (x: [N,512] fp32, W: [2,512,128] fp32)
// Block: 256 threads computes a 64-row x 128-col tile for one support.
// Inner loop reads are all ds_read_b128: x staged TRANSPOSED in LDS.
// Thread (tx=t&15, ty=t>>4) computes rows ty*4..+3, cols {tx*4..+3, 64+tx*4..+3}
// (split column groups keep LDS W-reads at <=2-way bank aliasing).
// ---------------------------------------------------------------------------
__global__ __launch_bounds__(256) void gemm_kernel(const float* __restrict__ x,
                                                   const float* __restrict__ w,
                                                   float* __restrict__ pre) {
    __shared__ float xs_t[16][68];   // [k][row], stride 68 floats = 272B (16B aligned)
    __shared__ float wld[16][128];   // [k][col]

    const int s  = blockIdx.y;
    const int r0 = blockIdx.x * 64;
    const int t  = threadIdx.x;
    const int tx = t & 15;
    const int ty = t >> 4;
    const float* wbase = w + (size_t)s * (D_IN * D_OUT);

    float acc[4][8];
#pragma unroll
    for (int i = 0; i < 4; ++i)
#pragma unroll
        for (int j = 0; j < 8; ++j) acc[i][j] = 0.f;

    const int xrow  = t >> 2;        // 0..63
    const int xquad = (t & 3) * 4;   // 0,4,8,12

    for (int k0 = 0; k0 < D_IN; k0 += 16) {
        // --- stage x tile (transposed) ---
        const int gr = r0 + xrow;
        float4 xv = make_float4(0.f, 0.f, 0.f, 0.f);
        if (gr < N_NODES)
            xv = *(const float4*)(x + (size_t)gr * D_IN + k0 + xquad);
        xs_t[xquad + 0][xrow] = xv.x;
        xs_t[xquad + 1][xrow] = xv.y;
        xs_t[xquad + 2][xrow] = xv.z;
        xs_t[xquad + 3][xrow] = xv.w;
        // --- stage W tile: 16x128 floats = 512 float4, 2 per thread ---
#pragma unroll
        for (int q = 0; q < 2; ++q) {
            const int idx = q * 256 + t;        // 0..511
            const int kk  = idx >> 5;           // 0..15
            const int c4  = idx & 31;           // float4 index in row
            float4 wv = *(const float4*)(wbase + (size_t)(k0 + kk) * D_OUT + c4 * 4);
            *(float4*)(&wld[kk][c4 * 4]) = wv;
        }
        __syncthreads();

#pragma unroll
        for (int kk = 0; kk < 16; ++kk) {
            float4 xv4 = *(const float4*)(&xs_t[kk][ty * 4]);
            float4 w0  = *(const float4*)(&wld[kk][tx * 4]);
            float4 w1  = *(const float4*)(&wld[kk][64 + tx * 4]);
            float xr[4] = {xv4.x, xv4.y, xv4.z, xv4.w};
            float wr[8] = {w0.x, w0.y, w0.z, w0.w, w1.x, w1.y, w1.z, w1.w};
#pragma unroll
            for (int i = 0; i < 4; ++i)
#pragma unroll
                for (int j = 0; j < 8; ++j)
                    acc[i][j] += xr[i] * wr[j];
        }
        __syncthreads();
    }

    // --- epilogue: store pre[s][row][col] ---
#pragma unroll
    for (int i = 0; i < 4; ++i) {
        const int gr = r0 + ty * 4 + i;
        if (gr < N_NODES) {
            float* dst = pre + ((size_t)s * N_NODES + gr) * D_OUT;
            float4 a = make_float4(acc[i][0], acc[i][1], acc[i][2], acc[i][3]);
            float4 b = make_float4(acc[i][4], acc[i][5], acc[i][6], acc[i][7]);
            *(float4*)(dst + tx * 4)      = a;
            *(float4*)(dst + 64 + tx * 4) = b;
        }
    }
}

// ---------------------------------------------------------------------------
// SpMM scatter: out[row] += val * pre[s][col]   (atomics, one wave per edge)
// grid: (E/4, N_SUP), block 256 (4 waves). Lane handles 2 floats.
// ---------------------------------------------------------------------------
__global__ __launch_bounds__(256) void spmm_atomic(const float* __restrict__ adj_vals,
                                                   const int* __restrict__ adj_rows,
                                                   const int* __restrict__ adj_cols,
                                                   const float* __restrict__ pre,
                                                   float* __restrict__ out) {
    const int s    = blockIdx.y;
    const int wid  = (blockIdx.x * blockDim.x + threadIdx.x) >> 6;  // edge id
    const int lane = threadIdx.x & 63;
    if (wid >= N_EDGES) return;

    const float v = adj_vals[(size_t)s * N_EDGES + wid];
    const int   r = adj_rows[(size_t)s * N_EDGES + wid];
    const int   c = adj_cols[(size_t)s * N_EDGES + wid];

    const float* psrc = pre + ((size_t)s * N_NODES + c) * D_OUT + lane * 2;
    const float2 p = *(const float2*)psrc;

    float* o = out + (size_t)r * D_OUT + lane * 2;
    atomicAdd(o + 0, p.x * v);
    atomicAdd(o + 1, p.y * v);
}

// ---------------------------------------------------------------------------
// Epilogue: out = relu(out + bias), in place, float4
// ---------------------------------------------------------------------------
__global__ __launch_bounds__(256) void bias_relu(float* __restrict__ out,
                                                 const float* __restrict__ bias) {
    const int i = blockIdx.x * 256 + threadIdx.x;      // float4 index
    const int total4 = N_NODES * D_OUT / 4;
    if (i >= total4) return;
    const int c4 = (i * 4) & (D_OUT - 1);
    float4 v = *(float4*)(out + (size_t)i * 4);
    float4 b = *(const float4*)(bias + c4);
    v.x = fmaxf(v.x + b.x, 0.f);
    v.y = fmaxf(v.y + b.y, 0.f);
    v.z = fmaxf(v.z + b.z, 0.f);
    v.w = fmaxf(v.w + b.w, 0.f);
    *(float4*)(out + (size_t)i * 4) = v;
}

extern "C" void kernel_launch(void* const* d_in, const int* in_sizes, int n_in,
                              void* d_out, int out_size, void* d_ws, size_t ws_size,
                              hipStream_t stream) {
    const float* x        = (const float*)d_in[0];
    const float* kernels  = (const float*)d_in[1];
    const float* bias     = (const float*)d_in[2];
    const float* adj_vals = (const float*)d_in[3];
    const int*   adj_rows = (const int*)d_in[4];
    const int*   adj_cols = (const int*)d_in[5];
    float* out = (float*)d_out;
    float* pre = (float*)d_ws;   // [2][N_NODES][128] fp32 = 51.2 MB

    // zero-init accumulator (d_out is poisoned 0xAA before every call)
    hipMemsetAsync(d_out, 0, sizeof(float) * N_NODES * D_OUT, stream);

    dim3 g1((N_NODES + 63) / 64, N_SUP);
    gemm_kernel<<<g1, 256, 0, stream>>>(x, kernels, pre);

    dim3 g2((N_EDGES + 3) / 4, N_SUP);
    spmm_atomic<<<g2, 256, 0, stream>>>(adj_vals, adj_rows, adj_cols, pre, out);

    const int total4 = N_NODES * D_OUT / 4;
    bias_relu<<<(total4 + 255) / 256, 256, 0, stream>>>(out, bias);
}

// Round 2
// 603.027 us; speedup vs baseline: 2.6858x; 2.6858x over previous
//
#include <hip/hip_runtime.h>

#define N_NODES 50000
#define N_EDGES 800000
#define D_IN    512
#define D_OUT   128
#define N_SUP   2
#define BINS    (N_SUP * N_NODES)          // 100000 row-bins (support-major)
#define SCAN_ITEMS 1024                    // items per scan block (256 thr x 4)
#define SCAN_BLOCKS ((BINS + SCAN_ITEMS - 1) / SCAN_ITEMS)   // 98

// ---------------------------------------------------------------------------
// GEMM: pre[s] = x @ kernels[s]   (x: [N,512] fp32, W: [2,512,128] fp32)
// 256 threads -> 64-row x 128-col tile. x staged transposed in LDS so the
// inner loop is pure ds_read_b128 + FMA.
// ---------------------------------------------------------------------------
__global__ __launch_bounds__(256) void gemm_kernel(const float* __restrict__ x,
                                                   const float* __restrict__ w,
                                                   float* __restrict__ pre) {
    __shared__ float xs_t[16][68];
    __shared__ float wld[16][128];

    const int s  = blockIdx.y;
    const int r0 = blockIdx.x * 64;
    const int t  = threadIdx.x;
    const int tx = t & 15;
    const int ty = t >> 4;
    const float* wbase = w + (size_t)s * (D_IN * D_OUT);

    float acc[4][8];
#pragma unroll
    for (int i = 0; i < 4; ++i)
#pragma unroll
        for (int j = 0; j < 8; ++j) acc[i][j] = 0.f;

    const int xrow  = t >> 2;
    const int xquad = (t & 3) * 4;

    for (int k0 = 0; k0 < D_IN; k0 += 16) {
        const int gr = r0 + xrow;
        float4 xv = make_float4(0.f, 0.f, 0.f, 0.f);
        if (gr < N_NODES)
            xv = *(const float4*)(x + (size_t)gr * D_IN + k0 + xquad);
        xs_t[xquad + 0][xrow] = xv.x;
        xs_t[xquad + 1][xrow] = xv.y;
        xs_t[xquad + 2][xrow] = xv.z;
        xs_t[xquad + 3][xrow] = xv.w;
#pragma unroll
        for (int q = 0; q < 2; ++q) {
            const int idx = q * 256 + t;
            const int kk  = idx >> 5;
            const int c4  = idx & 31;
            float4 wv = *(const float4*)(wbase + (size_t)(k0 + kk) * D_OUT + c4 * 4);
            *(float4*)(&wld[kk][c4 * 4]) = wv;
        }
        __syncthreads();

#pragma unroll
        for (int kk = 0; kk < 16; ++kk) {
            float4 xv4 = *(const float4*)(&xs_t[kk][ty * 4]);
            float4 w0  = *(const float4*)(&wld[kk][tx * 4]);
            float4 w1  = *(const float4*)(&wld[kk][64 + tx * 4]);
            float xr[4] = {xv4.x, xv4.y, xv4.z, xv4.w};
            float wr[8] = {w0.x, w0.y, w0.z, w0.w, w1.x, w1.y, w1.z, w1.w};
#pragma unroll
            for (int i = 0; i < 4; ++i)
#pragma unroll
                for (int j = 0; j < 8; ++j)
                    acc[i][j] += xr[i] * wr[j];
        }
        __syncthreads();
    }

#pragma unroll
    for (int i = 0; i < 4; ++i) {
        const int gr = r0 + ty * 4 + i;
        if (gr < N_NODES) {
            float* dst = pre + ((size_t)s * N_NODES + gr) * D_OUT;
            float4 a = make_float4(acc[i][0], acc[i][1], acc[i][2], acc[i][3]);
            float4 b = make_float4(acc[i][4], acc[i][5], acc[i][6], acc[i][7]);
            *(float4*)(dst + tx * 4)      = a;
            *(float4*)(dst + 64 + tx * 4) = b;
        }
    }
}

// ---------------------------------------------------------------------------
// Counting sort of edges by destination row (per support).
// ---------------------------------------------------------------------------
__global__ __launch_bounds__(256) void histogram_kernel(const int* __restrict__ adj_rows,
                                                        int* __restrict__ counts) {
    const int s = blockIdx.y;
    const int e = blockIdx.x * 256 + threadIdx.x;
    if (e >= N_EDGES) return;
    const int r = adj_rows[(size_t)s * N_EDGES + e];
    atomicAdd(&counts[s * N_NODES + r], 1);
}

// per-block exclusive scan (256 thr x 4 items), block totals to blocksums
__global__ __launch_bounds__(256) void scan_a(const int* __restrict__ counts,
                                              int* __restrict__ offsets,
                                              int* __restrict__ blocksums) {
    __shared__ int sdata[256];
    const int b    = blockIdx.x;
    const int t    = threadIdx.x;
    const int base = b * SCAN_ITEMS + t * 4;
    int v[4];
#pragma unroll
    for (int i = 0; i < 4; ++i) {
        const int idx = base + i;
        v[i] = (idx < BINS) ? counts[idx] : 0;
    }
    int tsum = v[0] + v[1] + v[2] + v[3];
    sdata[t] = tsum;
    __syncthreads();
    for (int off = 1; off < 256; off <<= 1) {
        int xv = (t >= off) ? sdata[t - off] : 0;
        __syncthreads();
        sdata[t] += xv;
        __syncthreads();
    }
    int run = sdata[t] - tsum;   // exclusive prefix of this thread
    if (t == 255) blocksums[b] = sdata[255];
#pragma unroll
    for (int i = 0; i < 4; ++i) {
        const int idx = base + i;
        if (idx < BINS) offsets[idx] = run;
        run += v[i];
    }
}

// serial exclusive scan of the 98 block sums (single tiny kernel)
__global__ void scan_b(int* __restrict__ blocksums) {
    if (threadIdx.x == 0 && blockIdx.x == 0) {
        int run = 0;
        for (int b = 0; b < SCAN_BLOCKS; ++b) {
            int c = blocksums[b];
            blocksums[b] = run;
            run += c;
        }
    }
}

// add block offsets; also initialize the scatter cursor
__global__ __launch_bounds__(256) void scan_c(int* __restrict__ offsets,
                                              const int* __restrict__ blocksums,
                                              int* __restrict__ cursor) {
    const int idx = blockIdx.x * SCAN_ITEMS + threadIdx.x * 4;
    const int add = blocksums[blockIdx.x];
#pragma unroll
    for (int i = 0; i < 4; ++i) {
        const int k = idx + i;
        if (k < BINS) {
            const int o = offsets[k] + add;
            offsets[k] = o;
            cursor[k]  = o;
        }
    }
}

__global__ __launch_bounds__(256) void scatter_kernel(const float* __restrict__ adj_vals,
                                                      const int* __restrict__ adj_rows,
                                                      const int* __restrict__ adj_cols,
                                                      int* __restrict__ cursor,
                                                      float* __restrict__ sorted_val,
                                                      int* __restrict__ sorted_col) {
    const int s = blockIdx.y;
    const int e = blockIdx.x * 256 + threadIdx.x;
    if (e >= N_EDGES) return;
    const size_t src = (size_t)s * N_EDGES + e;
    const int   r = adj_rows[src];
    const int   c = adj_cols[src];
    const float v = adj_vals[src];
    const int pos = atomicAdd(&cursor[s * N_NODES + r], 1);
    sorted_val[pos] = v;
    sorted_col[pos] = c;
}

// ---------------------------------------------------------------------------
// Gather SpMM + bias + ReLU, fused. One wave per output row; each lane owns
// 2 of the 128 features. (col,val) broadcast via __shfl; 4-way unrolled for
// load-level parallelism. Writes each out element exactly once — no atomics.
// ---------------------------------------------------------------------------
__global__ __launch_bounds__(256) void gather_spmm(const int* __restrict__ offsets,
                                                   const int* __restrict__ counts,
                                                   const float* __restrict__ sorted_val,
                                                   const int* __restrict__ sorted_col,
                                                   const float* __restrict__ pre,
                                                   const float* __restrict__ bias,
                                                   float* __restrict__ out) {
    const int lane = threadIdx.x & 63;
    const int row  = blockIdx.x * 4 + (threadIdx.x >> 6);
    if (row >= N_NODES) return;

    float2 acc = make_float2(0.f, 0.f);

#pragma unroll
    for (int s = 0; s < N_SUP; ++s) {
        const int bin   = s * N_NODES + row;
        const int start = offsets[bin];
        const int cnt   = counts[bin];
        const float* psup = pre + (size_t)s * N_NODES * D_OUT;

        for (int e0 = 0; e0 < cnt; e0 += 64) {
            const int m = min(64, cnt - e0);
            int   c = 0;
            float v = 0.f;
            if (lane < m) {
                c = sorted_col[start + e0 + lane];
                v = sorted_val[start + e0 + lane];
            }
            int j = 0;
            for (; j + 3 < m; j += 4) {
                const int   c0 = __shfl(c, j + 0), c1 = __shfl(c, j + 1);
                const int   c2 = __shfl(c, j + 2), c3 = __shfl(c, j + 3);
                const float v0 = __shfl(v, j + 0), v1 = __shfl(v, j + 1);
                const float v2 = __shfl(v, j + 2), v3 = __shfl(v, j + 3);
                const float2 p0 = *(const float2*)(psup + (size_t)c0 * D_OUT + lane * 2);
                const float2 p1 = *(const float2*)(psup + (size_t)c1 * D_OUT + lane * 2);
                const float2 p2 = *(const float2*)(psup + (size_t)c2 * D_OUT + lane * 2);
                const float2 p3 = *(const float2*)(psup + (size_t)c3 * D_OUT + lane * 2);
                acc.x += v0 * p0.x; acc.y += v0 * p0.y;
                acc.x += v1 * p1.x; acc.y += v1 * p1.y;
                acc.x += v2 * p2.x; acc.y += v2 * p2.y;
                acc.x += v3 * p3.x; acc.y += v3 * p3.y;
            }
            for (; j < m; ++j) {
                const int   cc = __shfl(c, j);
                const float vv = __shfl(v, j);
                const float2 p = *(const float2*)(psup + (size_t)cc * D_OUT + lane * 2);
                acc.x += vv * p.x; acc.y += vv * p.y;
            }
        }
    }

    const float2 b = *(const float2*)(bias + lane * 2);
    acc.x = fmaxf(acc.x + b.x, 0.f);
    acc.y = fmaxf(acc.y + b.y, 0.f);
    *(float2*)(out + (size_t)row * D_OUT + lane * 2) = acc;
}

extern "C" void kernel_launch(void* const* d_in, const int* in_sizes, int n_in,
                              void* d_out, int out_size, void* d_ws, size_t ws_size,
                              hipStream_t stream) {
    const float* x        = (const float*)d_in[0];
    const float* kernels  = (const float*)d_in[1];
    const float* bias     = (const float*)d_in[2];
    const float* adj_vals = (const float*)d_in[3];
    const int*   adj_rows = (const int*)d_in[4];
    const int*   adj_cols = (const int*)d_in[5];
    float* out = (float*)d_out;

    // ---- workspace layout (256B-aligned regions) ----
    char* ws = (char*)d_ws;
    size_t off = 0;
    auto alloc = [&](size_t bytes) {
        char* p = ws + off;
        off += (bytes + 255) & ~(size_t)255;
        return p;
    };
    float* pre        = (float*)alloc(sizeof(float) * N_SUP * N_NODES * D_OUT); // 51.2 MB
    float* sorted_val = (float*)alloc(sizeof(float) * N_SUP * N_EDGES);         // 6.4 MB
    int*   sorted_col = (int*)  alloc(sizeof(int)   * N_SUP * N_EDGES);         // 6.4 MB
    int*   counts     = (int*)  alloc(sizeof(int)   * BINS);
    int*   offsets    = (int*)  alloc(sizeof(int)   * BINS);
    int*   cursor     = (int*)  alloc(sizeof(int)   * BINS);
    int*   blocksums  = (int*)  alloc(sizeof(int)   * SCAN_BLOCKS);

    // ---- dense GEMM: pre[s] = x @ W[s] ----
    dim3 g1((N_NODES + 63) / 64, N_SUP);
    gemm_kernel<<<g1, 256, 0, stream>>>(x, kernels, pre);

    // ---- counting sort of edges by row ----
    hipMemsetAsync(counts, 0, sizeof(int) * BINS, stream);
    dim3 ge((N_EDGES + 255) / 256, N_SUP);
    histogram_kernel<<<ge, 256, 0, stream>>>(adj_rows, counts);
    scan_a<<<SCAN_BLOCKS, 256, 0, stream>>>(counts, offsets, blocksums);
    scan_b<<<1, 64, 0, stream>>>(blocksums);
    scan_c<<<SCAN_BLOCKS, 256, 0, stream>>>(offsets, blocksums, cursor);
    scatter_kernel<<<ge, 256, 0, stream>>>(adj_vals, adj_rows, adj_cols,
                                           cursor, sorted_val, sorted_col);

    // ---- gather SpMM + bias + ReLU (one wave per row) ----
    gather_spmm<<<(N_NODES + 3) / 4, 256, 0, stream>>>(offsets, counts, sorted_val,
                                                       sorted_col, pre, bias, out);
}

// Round 3
// 440.764 us; speedup vs baseline: 3.6746x; 1.3681x over previous
//
#include <hip/hip_runtime.h>

#define N_NODES 50000
#define N_EDGES 800000
#define D_IN    512
#define D_OUT   128
#define N_SUP   2
#define N_COLS  (N_SUP * D_OUT)            // 256 combined output cols
#define BINS    (N_SUP * N_NODES)          // 100000 row-bins (support-major)
#define SCAN_ITEMS 1024
#define SCAN_BLOCKS ((BINS + SCAN_ITEMS - 1) / SCAN_ITEMS)   // 98

typedef __attribute__((ext_vector_type(8))) __bf16 bf16x8;
typedef __attribute__((ext_vector_type(4))) float  f32x4;

// ---------------------------------------------------------------------------
// W convert: kernels [2][512][128] fp32 -> wt2 bf16 in STAGING ORDER:
// chunk g = kq*256 + n  (kq = k>>3, n = s*128 + n'), 8 bf16 per chunk (k-octet)
// so the GEMM's global_load_lds reads are contiguous.
// ---------------------------------------------------------------------------
__global__ __launch_bounds__(256) void convert_w(const float* __restrict__ w,
                                                 __bf16* __restrict__ wt2) {
    const int g = blockIdx.x * 256 + threadIdx.x;     // 16384 chunks
    if (g >= (D_IN / 8) * N_COLS) return;
    const int kq = g >> 8;          // 0..63
    const int n  = g & 255;
    const int s  = n >> 7;
    const int np = n & 127;
    bf16x8 v;
#pragma unroll
    for (int j = 0; j < 8; ++j) {
        const int k = kq * 8 + j;
        v[j] = (__bf16)w[((size_t)s * D_IN + k) * D_OUT + np];
    }
    *(bf16x8*)(wt2 + (size_t)g * 8) = v;
}

// ---------------------------------------------------------------------------
// bf16 MFMA GEMM: pre[s] = bf16(x) @ bf16(W[s]), output stored bf16.
// Block = 256 thr (4 waves), 64 rows x 256 cols. Wave w owns rows w*16..+15,
// all 256 cols -> x read exactly once from HBM (fp32, converted in-reg).
// B staged in LDS via global_load_lds(16B) from wt2; BK=64 per stage.
// mfma_f32_16x16x32_bf16: A[m=lane&15][k=quad*8+j], B[k][n=lane&15],
// D: col=lane&15, row=quad*4+reg  [m89-verified mapping].
// ---------------------------------------------------------------------------
__global__ __launch_bounds__(256) void gemm_bf16(const float* __restrict__ x,
                                                 const __bf16* __restrict__ wt2,
                                                 __bf16* __restrict__ pre) {
    __shared__ __align__(16) __bf16 Bs[2048 * 8];   // 32 KB: 2048 16B-chunks

    const int t    = threadIdx.x;
    const int lane = t & 63;
    const int w    = t >> 6;
    const int l15  = lane & 15;
    const int quad = lane >> 4;

    const int rbase = blockIdx.x * 64 + w * 16;
    int arow = rbase + l15;
    if (arow >= N_NODES) arow = N_NODES - 1;          // clamp: loads valid, store guarded
    const float* aptr = x + (size_t)arow * D_IN + quad * 8;

    f32x4 acc[16];
#pragma unroll
    for (int i = 0; i < 16; ++i) acc[i] = (f32x4)0.f;

    for (int kb = 0; kb < 8; ++kb) {                  // BK = 64
        // --- stage B: 2048 chunks of 16B, 8 per thread, coalesced 1KB/wave ---
        const __bf16* gsrc = wt2 + ((size_t)kb * 2048 + w * 64 + lane) * 8;
#pragma unroll
        for (int i = 0; i < 8; ++i) {
            __builtin_amdgcn_global_load_lds(
                (const __attribute__((address_space(1))) unsigned int*)(gsrc + (size_t)i * 2048),
                (__attribute__((address_space(3))) unsigned int*)(&Bs[(i * 256 + w * 64) * 8]),
                16, 0, 0);
        }
        // --- A frags: 16 fp32 from global, cvt to bf16 in-reg ---
        bf16x8 afrag[2];
#pragma unroll
        for (int kk = 0; kk < 2; ++kk) {
            const float* ap = aptr + kb * 64 + kk * 32;
            float4 f0 = *(const float4*)(ap);
            float4 f1 = *(const float4*)(ap + 4);
            bf16x8 a;
            a[0] = (__bf16)f0.x; a[1] = (__bf16)f0.y;
            a[2] = (__bf16)f0.z; a[3] = (__bf16)f0.w;
            a[4] = (__bf16)f1.x; a[5] = (__bf16)f1.y;
            a[6] = (__bf16)f1.z; a[7] = (__bf16)f1.w;
            afrag[kk] = a;
        }
        __syncthreads();   // drains global_load_lds (vmcnt) before LDS reads

#pragma unroll
        for (int kk = 0; kk < 2; ++kk) {
            const __bf16* bbase = &Bs[((kk * 4 + quad) * 256 + l15) * 8];
#pragma unroll
            for (int ct = 0; ct < 16; ++ct) {
                bf16x8 b = *(const bf16x8*)(bbase + ct * 128);   // 2-way bank alias: free
                acc[ct] = __builtin_amdgcn_mfma_f32_16x16x32_bf16(afrag[kk], b, acc[ct], 0, 0, 0);
            }
        }
        __syncthreads();   // protect Bs before next stage overwrites
    }

    // --- epilogue: D[row=rbase+quad*4+r][col=ct*16+l15], store bf16 ---
#pragma unroll
    for (int ct = 0; ct < 16; ++ct) {
        const int col = ct * 16 + l15;
        const int s   = col >> 7;
        const int cp  = col & 127;
#pragma unroll
        for (int r = 0; r < 4; ++r) {
            const int row = rbase + quad * 4 + r;
            if (row < N_NODES)
                pre[((size_t)s * N_NODES + row) * D_OUT + cp] = (__bf16)acc[ct][r];
        }
    }
}

// ---------------------------------------------------------------------------
// Counting sort of edges by destination row (per support).
// ---------------------------------------------------------------------------
__global__ __launch_bounds__(256) void histogram_kernel(const int* __restrict__ adj_rows,
                                                        int* __restrict__ counts) {
    const int s = blockIdx.y;
    const int e = blockIdx.x * 256 + threadIdx.x;
    if (e >= N_EDGES) return;
    const int r = adj_rows[(size_t)s * N_EDGES + e];
    atomicAdd(&counts[s * N_NODES + r], 1);
}

__global__ __launch_bounds__(256) void scan_a(const int* __restrict__ counts,
                                              int* __restrict__ offsets,
                                              int* __restrict__ blocksums) {
    __shared__ int sdata[256];
    const int b    = blockIdx.x;
    const int t    = threadIdx.x;
    const int base = b * SCAN_ITEMS + t * 4;
    int v[4];
#pragma unroll
    for (int i = 0; i < 4; ++i) {
        const int idx = base + i;
        v[i] = (idx < BINS) ? counts[idx] : 0;
    }
    int tsum = v[0] + v[1] + v[2] + v[3];
    sdata[t] = tsum;
    __syncthreads();
    for (int off = 1; off < 256; off <<= 1) {
        int xv = (t >= off) ? sdata[t - off] : 0;
        __syncthreads();
        sdata[t] += xv;
        __syncthreads();
    }
    int run = sdata[t] - tsum;
    if (t == 255) blocksums[b] = sdata[255];
#pragma unroll
    for (int i = 0; i < 4; ++i) {
        const int idx = base + i;
        if (idx < BINS) offsets[idx] = run;
        run += v[i];
    }
}

__global__ void scan_b(int* __restrict__ blocksums) {
    if (threadIdx.x == 0 && blockIdx.x == 0) {
        int run = 0;
        for (int b = 0; b < SCAN_BLOCKS; ++b) {
            int c = blocksums[b];
            blocksums[b] = run;
            run += c;
        }
    }
}

__global__ __launch_bounds__(256) void scan_c(int* __restrict__ offsets,
                                              const int* __restrict__ blocksums,
                                              int* __restrict__ cursor) {
    const int idx = blockIdx.x * SCAN_ITEMS + threadIdx.x * 4;
    const int add = blocksums[blockIdx.x];
#pragma unroll
    for (int i = 0; i < 4; ++i) {
        const int k = idx + i;
        if (k < BINS) {
            const int o = offsets[k] + add;
            offsets[k] = o;
            cursor[k]  = o;
        }
    }
}

// scatter edges into row-sorted order; (val,col) packed as uint2
__global__ __launch_bounds__(256) void scatter_kernel(const float* __restrict__ adj_vals,
                                                      const int* __restrict__ adj_rows,
                                                      const int* __restrict__ adj_cols,
                                                      int* __restrict__ cursor,
                                                      uint2* __restrict__ sorted) {
    const int s = blockIdx.y;
    const int e = blockIdx.x * 256 + threadIdx.x;
    if (e >= N_EDGES) return;
    const size_t src = (size_t)s * N_EDGES + e;
    const int   r = adj_rows[src];
    const int   c = adj_cols[src];
    const float v = adj_vals[src];
    const int pos = atomicAdd(&cursor[s * N_NODES + r], 1);
    sorted[pos] = make_uint2(__float_as_uint(v), (unsigned)c);
}

// ---------------------------------------------------------------------------
// Gather SpMM + bias + ReLU. One wave per row, lane owns 2 features.
// pre is bf16 -> one dword load per (edge,lane), unpacked by bit-shift.
// ---------------------------------------------------------------------------
__global__ __launch_bounds__(256) void gather_spmm(const int* __restrict__ offsets,
                                                   const int* __restrict__ counts,
                                                   const uint2* __restrict__ sorted,
                                                   const unsigned int* __restrict__ pre_u, // bf16x2 view
                                                   const float* __restrict__ bias,
                                                   float* __restrict__ out) {
    const int lane = threadIdx.x & 63;
    const int row  = blockIdx.x * 4 + (threadIdx.x >> 6);
    if (row >= N_NODES) return;

    float2 acc = make_float2(0.f, 0.f);

#pragma unroll
    for (int s = 0; s < N_SUP; ++s) {
        const int bin   = s * N_NODES + row;
        const int start = offsets[bin];
        const int cnt   = counts[bin];
        const unsigned int* psup = pre_u + (size_t)s * N_NODES * (D_OUT / 2) + lane;

        for (int e0 = 0; e0 < cnt; e0 += 64) {
            const int m = min(64, cnt - e0);
            int   c = 0;
            float v = 0.f;
            if (lane < m) {
                uint2 ed = sorted[start + e0 + lane];
                v = __uint_as_float(ed.x);
                c = (int)ed.y;
            }
            int j = 0;
            for (; j + 3 < m; j += 4) {
                const int   c0 = __shfl(c, j + 0), c1 = __shfl(c, j + 1);
                const int   c2 = __shfl(c, j + 2), c3 = __shfl(c, j + 3);
                const float v0 = __shfl(v, j + 0), v1 = __shfl(v, j + 1);
                const float v2 = __shfl(v, j + 2), v3 = __shfl(v, j + 3);
                const unsigned u0 = psup[(size_t)c0 * 64];
                const unsigned u1 = psup[(size_t)c1 * 64];
                const unsigned u2 = psup[(size_t)c2 * 64];
                const unsigned u3 = psup[(size_t)c3 * 64];
                acc.x += v0 * __uint_as_float(u0 << 16);
                acc.y += v0 * __uint_as_float(u0 & 0xffff0000u);
                acc.x += v1 * __uint_as_float(u1 << 16);
                acc.y += v1 * __uint_as_float(u1 & 0xffff0000u);
                acc.x += v2 * __uint_as_float(u2 << 16);
                acc.y += v2 * __uint_as_float(u2 & 0xffff0000u);
                acc.x += v3 * __uint_as_float(u3 << 16);
                acc.y += v3 * __uint_as_float(u3 & 0xffff0000u);
            }
            for (; j < m; ++j) {
                const int   cc = __shfl(c, j);
                const float vv = __shfl(v, j);
                const unsigned u = psup[(size_t)cc * 64];
                acc.x += vv * __uint_as_float(u << 16);
                acc.y += vv * __uint_as_float(u & 0xffff0000u);
            }
        }
    }

    const float2 b = *(const float2*)(bias + lane * 2);
    acc.x = fmaxf(acc.x + b.x, 0.f);
    acc.y = fmaxf(acc.y + b.y, 0.f);
    *(float2*)(out + (size_t)row * D_OUT + lane * 2) = acc;
}

extern "C" void kernel_launch(void* const* d_in, const int* in_sizes, int n_in,
                              void* d_out, int out_size, void* d_ws, size_t ws_size,
                              hipStream_t stream) {
    const float* x        = (const float*)d_in[0];
    const float* kernels  = (const float*)d_in[1];
    const float* bias     = (const float*)d_in[2];
    const float* adj_vals = (const float*)d_in[3];
    const int*   adj_rows = (const int*)d_in[4];
    const int*   adj_cols = (const int*)d_in[5];
    float* out = (float*)d_out;

    // ---- workspace layout ----
    char* ws = (char*)d_ws;
    size_t off = 0;
    auto alloc = [&](size_t bytes) {
        char* p = ws + off;
        off += (bytes + 255) & ~(size_t)255;
        return p;
    };
    __bf16* pre    = (__bf16*)alloc(sizeof(__bf16) * N_SUP * N_NODES * D_OUT); // 25.6 MB
    __bf16* wt2    = (__bf16*)alloc(sizeof(__bf16) * D_IN * N_COLS);           // 256 KB
    uint2*  sorted = (uint2*) alloc(sizeof(uint2)  * N_SUP * N_EDGES);         // 12.8 MB
    int*    counts    = (int*)alloc(sizeof(int) * BINS);
    int*    offsets   = (int*)alloc(sizeof(int) * BINS);
    int*    cursor    = (int*)alloc(sizeof(int) * BINS);
    int*    blocksums = (int*)alloc(sizeof(int) * SCAN_BLOCKS);

    // ---- W -> bf16 staging layout ----
    convert_w<<<(D_IN / 8) * N_COLS / 256, 256, 0, stream>>>(kernels, wt2);

    // ---- bf16 MFMA GEMM ----
    gemm_bf16<<<(N_NODES + 63) / 64, 256, 0, stream>>>(x, wt2, pre);

    // ---- counting sort of edges by row ----
    hipMemsetAsync(counts, 0, sizeof(int) * BINS, stream);
    dim3 ge((N_EDGES + 255) / 256, N_SUP);
    histogram_kernel<<<ge, 256, 0, stream>>>(adj_rows, counts);
    scan_a<<<SCAN_BLOCKS, 256, 0, stream>>>(counts, offsets, blocksums);
    scan_b<<<1, 64, 0, stream>>>(blocksums);
    scan_c<<<SCAN_BLOCKS, 256, 0, stream>>>(offsets, blocksums, cursor);
    scatter_kernel<<<ge, 256, 0, stream>>>(adj_vals, adj_rows, adj_cols, cursor, sorted);

    // ---- gather SpMM + bias + ReLU ----
    gather_spmm<<<(N_NODES + 3) / 4, 256, 0, stream>>>(offsets, counts, sorted,
                                                       (const unsigned int*)pre, bias, out);
}

// Round 4
// 300.004 us; speedup vs baseline: 5.3986x; 1.4692x over previous
//
#include <hip/hip_runtime.h>

#define N_NODES 50000
#define N_EDGES 800000
#define D_IN    512
#define D_OUT   128
#define N_SUP   2
#define N_COLS  (N_SUP * D_OUT)            // 256 combined output cols
#define BINS    (N_SUP * N_NODES)          // 100000 row-bins (support-major)
#define NB_S    196                        // coarse buckets per support (256 rows each)
#define NB      (N_SUP * NB_S)             // 392 total coarse buckets
#define CHUNK   4096                       // edges per block in coarse pass
#define NCHUNK  ((N_EDGES + CHUNK - 1) / CHUNK)   // 196 blocks per support

typedef __attribute__((ext_vector_type(8))) __bf16 bf16x8;
typedef __attribute__((ext_vector_type(4))) float  f32x4;

// ---------------------------------------------------------------------------
// W convert: kernels [2][512][128] fp32 -> wt2 bf16 in GEMM staging order.
// ---------------------------------------------------------------------------
__global__ __launch_bounds__(256) void convert_w(const float* __restrict__ w,
                                                 __bf16* __restrict__ wt2) {
    const int g = blockIdx.x * 256 + threadIdx.x;     // 16384 chunks
    if (g >= (D_IN / 8) * N_COLS) return;
    const int kq = g >> 8;
    const int n  = g & 255;
    const int s  = n >> 7;
    const int np = n & 127;
    bf16x8 v;
#pragma unroll
    for (int j = 0; j < 8; ++j) {
        const int k = kq * 8 + j;
        v[j] = (__bf16)w[((size_t)s * D_IN + k) * D_OUT + np];
    }
    *(bf16x8*)(wt2 + (size_t)g * 8) = v;
}

// ---------------------------------------------------------------------------
// bf16 MFMA GEMM: pre[s] = bf16(x) @ bf16(W[s]), output bf16. (round-3 kernel)
// ---------------------------------------------------------------------------
__global__ __launch_bounds__(256) void gemm_bf16(const float* __restrict__ x,
                                                 const __bf16* __restrict__ wt2,
                                                 __bf16* __restrict__ pre) {
    __shared__ __align__(16) __bf16 Bs[2048 * 8];   // 32 KB

    const int t    = threadIdx.x;
    const int lane = t & 63;
    const int w    = t >> 6;
    const int l15  = lane & 15;
    const int quad = lane >> 4;

    const int rbase = blockIdx.x * 64 + w * 16;
    int arow = rbase + l15;
    if (arow >= N_NODES) arow = N_NODES - 1;
    const float* aptr = x + (size_t)arow * D_IN + quad * 8;

    f32x4 acc[16];
#pragma unroll
    for (int i = 0; i < 16; ++i) acc[i] = (f32x4)0.f;

    for (int kb = 0; kb < 8; ++kb) {                  // BK = 64
        const __bf16* gsrc = wt2 + ((size_t)kb * 2048 + w * 64 + lane) * 8;
#pragma unroll
        for (int i = 0; i < 8; ++i) {
            __builtin_amdgcn_global_load_lds(
                (const __attribute__((address_space(1))) unsigned int*)(gsrc + (size_t)i * 2048),
                (__attribute__((address_space(3))) unsigned int*)(&Bs[(i * 256 + w * 64) * 8]),
                16, 0, 0);
        }
        bf16x8 afrag[2];
#pragma unroll
        for (int kk = 0; kk < 2; ++kk) {
            const float* ap = aptr + kb * 64 + kk * 32;
            float4 f0 = *(const float4*)(ap);
            float4 f1 = *(const float4*)(ap + 4);
            bf16x8 a;
            a[0] = (__bf16)f0.x; a[1] = (__bf16)f0.y;
            a[2] = (__bf16)f0.z; a[3] = (__bf16)f0.w;
            a[4] = (__bf16)f1.x; a[5] = (__bf16)f1.y;
            a[6] = (__bf16)f1.z; a[7] = (__bf16)f1.w;
            afrag[kk] = a;
        }
        __syncthreads();

#pragma unroll
        for (int kk = 0; kk < 2; ++kk) {
            const __bf16* bbase = &Bs[((kk * 4 + quad) * 256 + l15) * 8];
#pragma unroll
            for (int ct = 0; ct < 16; ++ct) {
                bf16x8 b = *(const bf16x8*)(bbase + ct * 128);
                acc[ct] = __builtin_amdgcn_mfma_f32_16x16x32_bf16(afrag[kk], b, acc[ct], 0, 0, 0);
            }
        }
        __syncthreads();
    }

#pragma unroll
    for (int ct = 0; ct < 16; ++ct) {
        const int col = ct * 16 + l15;
        const int s   = col >> 7;
        const int cp  = col & 127;
#pragma unroll
        for (int r = 0; r < 4; ++r) {
            const int row = rbase + quad * 4 + r;
            if (row < N_NODES)
                pre[((size_t)s * N_NODES + row) * D_OUT + cp] = (__bf16)acc[ct][r];
        }
    }
}

// ---------------------------------------------------------------------------
// Coarse histogram: 196 buckets/support (256 rows each), LDS-binned.
// ---------------------------------------------------------------------------
__global__ __launch_bounds__(256) void hist_coarse(const int* __restrict__ adj_rows,
                                                   int* __restrict__ gcount) {
    __shared__ int lh[NB_S];
    const int s = blockIdx.y;
    const int t = threadIdx.x;
    if (t < NB_S) lh[t] = 0;
    __syncthreads();
    const int e0 = blockIdx.x * CHUNK;
#pragma unroll
    for (int i = 0; i < 16; ++i) {
        const int e = e0 + i * 256 + t;
        if (e < N_EDGES) {
            const int r = adj_rows[(size_t)s * N_EDGES + e];
            atomicAdd(&lh[r >> 8], 1);
        }
    }
    __syncthreads();
    if (t < NB_S && lh[t]) atomicAdd(&gcount[s * NB_S + t], lh[t]);
}

// single-block exclusive scan of the 392 bucket counts -> base & cursor
__global__ __launch_bounds__(256) void scan_coarse(const int* __restrict__ gcount,
                                                   int* __restrict__ base,
                                                   int* __restrict__ cursor) {
    __shared__ int sd[512];
    const int t  = threadIdx.x;
    const int i1 = t + 256;
    const int c0 = (t  < NB) ? gcount[t]  : 0;
    const int c1 = (i1 < NB) ? gcount[i1] : 0;
    sd[t] = c0; sd[i1] = c1;
    __syncthreads();
    for (int off = 1; off < 512; off <<= 1) {
        const int a0 = (t  >= off) ? sd[t  - off] : 0;
        const int a1 = (i1 >= off) ? sd[i1 - off] : 0;
        __syncthreads();
        sd[t] += a0; sd[i1] += a1;
        __syncthreads();
    }
    if (t < NB)  { const int b = sd[t]  - c0; base[t]  = b; cursor[t]  = b; }
    if (i1 < NB) { const int b = sd[i1] - c1; base[i1] = b; cursor[i1] = b; }
}

// ---------------------------------------------------------------------------
// Coarse scatter: block reserves one contiguous run per touched bucket, then
// writes its edges in ~21-slot runs (L2-hot lines -> ~1.4x write-back).
// Payload: (val_bits, r_local<<16 | col)
// ---------------------------------------------------------------------------
__global__ __launch_bounds__(256) void scatter_coarse(const float* __restrict__ adj_vals,
                                                      const int* __restrict__ adj_rows,
                                                      const int* __restrict__ adj_cols,
                                                      int* __restrict__ gcursor,
                                                      uint2* __restrict__ coarse) {
    __shared__ int lh[NB_S];
    __shared__ int lbase[NB_S];
    const int s = blockIdx.y;
    const int t = threadIdx.x;
    if (t < NB_S) lh[t] = 0;
    __syncthreads();

    const int e0 = blockIdx.x * CHUNK;
    int   rr[16]; int cc[16]; float vv[16];
#pragma unroll
    for (int i = 0; i < 16; ++i) {
        const int e = e0 + i * 256 + t;
        if (e < N_EDGES) {
            const size_t src = (size_t)s * N_EDGES + e;
            rr[i] = adj_rows[src];
            cc[i] = adj_cols[src];
            vv[i] = adj_vals[src];
            atomicAdd(&lh[rr[i] >> 8], 1);
        } else {
            rr[i] = -1; cc[i] = 0; vv[i] = 0.f;
        }
    }
    __syncthreads();
    if (t < NB_S) {
        lbase[t] = lh[t] ? atomicAdd(&gcursor[s * NB_S + t], lh[t]) : 0;
        lh[t] = 0;   // reuse as rank counter
    }
    __syncthreads();
#pragma unroll
    for (int i = 0; i < 16; ++i) {
        if (rr[i] >= 0) {
            const int b    = rr[i] >> 8;
            const int rank = atomicAdd(&lh[b], 1);
            coarse[lbase[b] + rank] =
                make_uint2(__float_as_uint(vv[i]),
                           ((unsigned)(rr[i] & 255) << 16) | (unsigned)cc[i]);
        }
    }
}

// ---------------------------------------------------------------------------
// Fine scatter: one block per coarse bucket. LDS 256-bin row histogram +
// scan; emits final (val,col) sorted-by-row + global per-row offsets/counts.
// All writes land in the bucket's ~33KB window -> L2-hot, ~1x write-back.
// ---------------------------------------------------------------------------
__global__ __launch_bounds__(256) void scatter_fine(const uint2* __restrict__ coarse,
                                                    const int* __restrict__ gcount,
                                                    const int* __restrict__ base,
                                                    uint2* __restrict__ sorted,
                                                    int* __restrict__ row_off,
                                                    int* __restrict__ row_cnt) {
    __shared__ int rh[256];
    __shared__ int sd[256];
    __shared__ int rbs[256];
    __shared__ int rc[256];
    const int bk = blockIdx.x;      // 0..195
    const int s  = blockIdx.y;
    const int t  = threadIdx.x;
    const int bkt  = s * NB_S + bk;
    const int b0   = base[bkt];
    const int cnt  = gcount[bkt];

    rh[t] = 0; rc[t] = 0;
    __syncthreads();
    for (int i = t; i < cnt; i += 256) {
        const uint2 ed = coarse[b0 + i];
        atomicAdd(&rh[ed.y >> 16], 1);
    }
    __syncthreads();
    const int myc = rh[t];
    sd[t] = myc;
    __syncthreads();
    for (int off = 1; off < 256; off <<= 1) {
        const int a = (t >= off) ? sd[t - off] : 0;
        __syncthreads();
        sd[t] += a;
        __syncthreads();
    }
    const int ex  = sd[t] - myc;          // exclusive prefix within bucket
    const int row = (bk << 8) + t;
    if (row < N_NODES) {
        row_off[s * N_NODES + row] = b0 + ex;
        row_cnt[s * N_NODES + row] = myc;
    }
    rbs[t] = b0 + ex;
    __syncthreads();
    for (int i = t; i < cnt; i += 256) {
        const uint2 ed = coarse[b0 + i];
        const int   rl = ed.y >> 16;
        const int rank = atomicAdd(&rc[rl], 1);
        sorted[rbs[rl] + rank] = make_uint2(ed.x, ed.y & 0xFFFFu);
    }
}

// ---------------------------------------------------------------------------
// Gather SpMM + bias + ReLU. One wave per row; lane half (0/1) takes
// even/odd edges; each lane loads uint2 = 4 bf16 features. Cross-half
// __shfl_xor(32) reduction, half-0 writes float4.
// ---------------------------------------------------------------------------
__global__ __launch_bounds__(256) void gather_spmm(const int* __restrict__ row_off,
                                                   const int* __restrict__ row_cnt,
                                                   const uint2* __restrict__ sorted,
                                                   const unsigned int* __restrict__ pre_u,
                                                   const float* __restrict__ bias,
                                                   float* __restrict__ out) {
    const int lane = threadIdx.x & 63;
    const int half = lane >> 5;
    const int fl   = lane & 31;            // features fl*4 .. fl*4+3
    const int row  = blockIdx.x * 4 + (threadIdx.x >> 6);
    if (row >= N_NODES) return;

    float a0 = 0.f, a1 = 0.f, a2 = 0.f, a3 = 0.f;

#pragma unroll
    for (int s = 0; s < N_SUP; ++s) {
        const int bin   = s * N_NODES + row;
        const int start = row_off[bin];
        const int cnt   = row_cnt[bin];
        const unsigned int* psup = pre_u + (size_t)s * N_NODES * 64 + fl * 2;

        for (int e0 = 0; e0 < cnt; e0 += 64) {
            const int m = min(64, cnt - e0);
            int   c = 0;
            float v = 0.f;
            if (lane < m) {
                const uint2 ed = sorted[start + e0 + lane];
                v = __uint_as_float(ed.x);
                c = (int)ed.y;
            }
            const int steps = (m + 1) >> 1;

            auto step = [&](int jj) {
                const int   idx = (jj < m) ? jj : 0;
                float vj = __shfl(v, idx);
                const int cj = __shfl(c, idx);
                if (jj >= m) vj = 0.f;
                const uint2 p = *(const uint2*)(psup + (size_t)cj * 64);
                a0 += vj * __uint_as_float(p.x << 16);
                a1 += vj * __uint_as_float(p.x & 0xffff0000u);
                a2 += vj * __uint_as_float(p.y << 16);
                a3 += vj * __uint_as_float(p.y & 0xffff0000u);
            };
            int j = 0;
            for (; j + 1 < steps; j += 2) {
                step(2 * j + half);
                step(2 * j + 2 + half);
            }
            if (j < steps) step(2 * j + half);
        }
    }

    a0 += __shfl_xor(a0, 32);
    a1 += __shfl_xor(a1, 32);
    a2 += __shfl_xor(a2, 32);
    a3 += __shfl_xor(a3, 32);

    if (half == 0) {
        const float4 b = *(const float4*)(bias + fl * 4);
        float4 o;
        o.x = fmaxf(a0 + b.x, 0.f);
        o.y = fmaxf(a1 + b.y, 0.f);
        o.z = fmaxf(a2 + b.z, 0.f);
        o.w = fmaxf(a3 + b.w, 0.f);
        *(float4*)(out + (size_t)row * D_OUT + fl * 4) = o;
    }
}

extern "C" void kernel_launch(void* const* d_in, const int* in_sizes, int n_in,
                              void* d_out, int out_size, void* d_ws, size_t ws_size,
                              hipStream_t stream) {
    const float* x        = (const float*)d_in[0];
    const float* kernels  = (const float*)d_in[1];
    const float* bias     = (const float*)d_in[2];
    const float* adj_vals = (const float*)d_in[3];
    const int*   adj_rows = (const int*)d_in[4];
    const int*   adj_cols = (const int*)d_in[5];
    float* out = (float*)d_out;

    // ---- workspace layout ----
    char* ws = (char*)d_ws;
    size_t off = 0;
    auto alloc = [&](size_t bytes) {
        char* p = ws + off;
        off += (bytes + 255) & ~(size_t)255;
        return p;
    };
    __bf16* pre    = (__bf16*)alloc(sizeof(__bf16) * N_SUP * N_NODES * D_OUT); // 25.6 MB
    __bf16* wt2    = (__bf16*)alloc(sizeof(__bf16) * D_IN * N_COLS);           // 256 KB
    uint2*  coarse = (uint2*) alloc(sizeof(uint2)  * N_SUP * N_EDGES);         // 12.8 MB
    uint2*  sorted = (uint2*) alloc(sizeof(uint2)  * N_SUP * N_EDGES);         // 12.8 MB
    int*    row_off = (int*)alloc(sizeof(int) * BINS);                         // 400 KB
    int*    row_cnt = (int*)alloc(sizeof(int) * BINS);                         // 400 KB
    int*    gcount  = (int*)alloc(sizeof(int) * NB);
    int*    gbase   = (int*)alloc(sizeof(int) * NB);
    int*    gcursor = (int*)alloc(sizeof(int) * NB);

    // ---- dense path ----
    convert_w<<<(D_IN / 8) * N_COLS / 256, 256, 0, stream>>>(kernels, wt2);
    gemm_bf16<<<(N_NODES + 63) / 64, 256, 0, stream>>>(x, wt2, pre);

    // ---- two-level counting sort of edges by row ----
    hipMemsetAsync(gcount, 0, sizeof(int) * NB, stream);
    dim3 gc(NCHUNK, N_SUP);
    hist_coarse<<<gc, 256, 0, stream>>>(adj_rows, gcount);
    scan_coarse<<<1, 256, 0, stream>>>(gcount, gbase, gcursor);
    scatter_coarse<<<gc, 256, 0, stream>>>(adj_vals, adj_rows, adj_cols, gcursor, coarse);
    dim3 gf(NB_S, N_SUP);
    scatter_fine<<<gf, 256, 0, stream>>>(coarse, gcount, gbase, sorted, row_off, row_cnt);

    // ---- gather SpMM + bias + ReLU ----
    gather_spmm<<<(N_NODES + 3) / 4, 256, 0, stream>>>(row_off, row_cnt, sorted,
                                                       (const unsigned int*)pre, bias, out);
}